// Round 6
// baseline (44.694 us; speedup 1.0000x reference)
//
#include <hip/hip_runtime.h>

// Maj3: out[b,o,h,w] = sum_{kh,c} sign( sum_{kw} x[b,c,h+kh-1,w+kw-1] * W[o,kw,kh,c] )
// x: (4,64,56,56) f32; W: (64,3,3,64) f32; out: (4,64,56,56) f32.
// Bit-exactness vs numpy required (integer output, threshold 1.36): no FMA
// contraction (contract(off) pragma — verified holding, absmax stable 1.0),
// same per-channel mul/add order, sign(0)=0 only from fully-pad rows (skipped).
//
// R6: VALU-issue-bound (R5: 43us, VALUBusy 65%, 7 VALU/sign). Process channel
// PAIRS with ext_vector_type(2) math -> v_pk_mul_f32/v_pk_add_f32 (VOP3P,
// 2 signs per instr, bit-exact elementwise IEEE). Weight pairs (c,c+1) are
// contiguous -> s_load_dwordx2 SGPR pair feeds VOP3P directly. Sign extract:
// 2 lshr + add3 per pair. ~35% fewer core VALU instrs. Structure = R5.

#define Cn 64
#define Hn 56
#define Wn 56
#define On 64
#define OG 4    // output channels per block (uniform -> scalar weight loads)
#define CH 32   // channels per wave (c-half)

typedef float    v2f __attribute__((ext_vector_type(2)));
typedef unsigned v2u __attribute__((ext_vector_type(2)));

__global__ __launch_bounds__(256, 7)
void maj3_kernel(const float* __restrict__ x,
                 const float* __restrict__ wt,
                 float* __restrict__ out)
{
#pragma clang fp contract(off)
    __shared__ int lds[2][OG][64];

    const int lane   = threadIdx.x & 63;
    // Wave-uniform; readfirstlane keeps rows/weight addresses on the scalar path.
    const int wave_u = __builtin_amdgcn_readfirstlane((int)(threadIdx.x >> 6));
    const int r      = wave_u & 1;        // row slot within block (0..1)
    const int chalf  = wave_u >> 1;       // 0 / 1: which 32-channel half
    const int bh     = blockIdx.x * 2 + r;        // 0..223
    const int b      = bh / Hn;
    const int h      = bh - b * Hn;
    const int og     = blockIdx.y * OG;   // block-uniform o base

    const int wc     = lane;              // pixel column; lanes >=56 inactive
    const bool act   = wc < Wn;

    // Clamped tap addresses (never OOB) + per-tap validity for zero padding.
    const int c0 = min(max(wc - 1, 0), Wn - 1);
    const int c1 = min(wc, Wn - 1);
    const int c2 = min(wc + 1, Wn - 1);
    const bool f0 = (wc >= 1);
    const bool f1 = act;
    const bool f2 = (wc + 1 < Wn);

    int acc[OG];
    #pragma unroll
    for (int i = 0; i < OG; ++i) acc[i] = 0;

    int nvalid = 0;
    const float* xb = x + b * (Cn * Hn * Wn) + chalf * (CH * Hn * Wn);

    for (int kh = 0; kh < 3; ++kh) {
        const int row = h + kh - 1;
        if (row < 0 || row >= Hn) continue;   // fully-pad row: sign(0)=0, skip
        ++nvalid;
        const float* xr = xb + row * Wn;
        #pragma unroll 4
        for (int c = 0; c < CH; c += 2) {
            const float* xcA = xr + c * (Hn * Wn);        // channel c
            const float* xcB = xcA + (Hn * Wn);           // channel c+1
            const float a0 = f0 ? xcA[c0] : 0.0f;
            const float a1 = f1 ? xcA[c1] : 0.0f;
            const float a2 = f2 ? xcA[c2] : 0.0f;
            const float b0 = f0 ? xcB[c0] : 0.0f;
            const float b1 = f1 ? xcB[c1] : 0.0f;
            const float b2 = f2 ? xcB[c2] : 0.0f;
            const v2f X0 = { a0, b0 };
            const v2f X1 = { a1, b1 };
            const v2f X2 = { a2, b2 };
            #pragma unroll
            for (int oo = 0; oo < OG; ++oo) {
                // W[o,kw,kh,c]: c-contiguous -> aligned float2 = SGPR pair.
                const float* wp = wt + (og + oo) * (3 * 3 * Cn) + kh * Cn
                                + chalf * CH + c;
                const v2f W0 = *(const v2f*)(wp + 0 * 3 * Cn);
                const v2f W1 = *(const v2f*)(wp + 1 * 3 * Cn);
                const v2f W2 = *(const v2f*)(wp + 2 * 3 * Cn);
                const v2f P0 = X0 * W0;          // v_pk_mul_f32 (contract off)
                const v2f P1 = X1 * W1;
                const v2f P2 = X2 * W2;
                const v2f S  = (P0 + P1) + P2;   // v_pk_add_f32, ref order
                const v2u U  = __builtin_bit_cast(v2u, S);
                acc[oo] += (int)(U.x >> 31) + (int)(U.y >> 31);  // lshr x2 + add3
            }
        }
    }

    // Combine the two c-halves' negative-counts (integer -> exact).
    if (chalf == 1) {
        #pragma unroll
        for (int oo = 0; oo < OG; ++oo) lds[r][oo][lane] = acc[oo];
    }
    __syncthreads();
    if (chalf == 0 && act) {
        float* ob = out + ((b * On + og) * Hn + h) * Wn + wc;
        const float base = (float)(nvalid * Cn);
        #pragma unroll
        for (int oo = 0; oo < OG; ++oo) {
            const int total = acc[oo] + lds[r][oo][lane];
            ob[oo * Hn * Wn] = base - 2.0f * (float)total;  // N - 2*negcount
        }
    }
}

extern "C" void kernel_launch(void* const* d_in, const int* in_sizes, int n_in,
                              void* d_out, int out_size, void* d_ws, size_t ws_size,
                              hipStream_t stream) {
    const float* x  = (const float*)d_in[0];
    const float* wt = (const float*)d_in[1];
    float* o        = (float*)d_out;
    dim3 grid(112, 16);   // 112 row-pair blocks x 16 o-groups of 4
    maj3_kernel<<<grid, dim3(256), 0, stream>>>(x, wt, o);
}

// Round 7
// 38.667 us; speedup vs baseline: 1.1559x; 1.1559x over previous
//
#include <hip/hip_runtime.h>

// Maj3: out[b,o,h,w] = sum_{kh,c} sign( sum_{kw} x[b,c,h+kh-1,w+kw-1] * W[o,kw,kh,c] )
// x: (4,64,56,56) f32; W: (64,3,3,64) f32; out: (4,64,56,56) f32.
// Bit-exactness vs numpy required (integer output, threshold 1.36): no FMA
// contraction (contract(off) pragma — verified holding, absmax stable 1.0),
// same per-channel mul/add order, sign(0)=0 only from fully-pad rows (skipped).
//
// R7: R6's packed-fp32 pairs were neutral (CDNA4 pk_f32 isn't double-rate) —
// reverted to R5 scalar core. New lever: the 3 tap loads per channel are the
// same wave-row shifted by one lane. Load ONCE, derive neighbors with DPP
// wave_shr1/wave_shl1 (EXEC-independent, bound lanes -> 0 = exact pad).
// Per c: 1 VMEM + 1 cndmask + 2 DPP vs 3 VMEM + 3 cndmask. VMEM issues /3.

#define Cn 64
#define Hn 56
#define Wn 56
#define On 64
#define OG 4    // output channels per block (uniform -> scalar weight loads)
#define CH 32   // channels per wave (c-half)

#define DPP_WAVE_SHL1 0x130
#define DPP_WAVE_SHR1 0x138

// Whole-wave shift by one lane; out-of-range source lanes read 0 (exact pad).
__device__ __forceinline__ float dpp_shift(float s, const int ctrl_is_shr) {
    const int si = __builtin_bit_cast(int, s);
    const int r  = ctrl_is_shr
        ? __builtin_amdgcn_update_dpp(0, si, DPP_WAVE_SHR1, 0xf, 0xf, true)
        : __builtin_amdgcn_update_dpp(0, si, DPP_WAVE_SHL1, 0xf, 0xf, true);
    return __builtin_bit_cast(float, r);
}

__global__ __launch_bounds__(256, 7)
void maj3_kernel(const float* __restrict__ x,
                 const float* __restrict__ wt,
                 float* __restrict__ out)
{
#pragma clang fp contract(off)
    __shared__ int lds[2][OG][64];

    const int lane   = threadIdx.x & 63;
    // Wave-uniform; readfirstlane keeps rows/weight addresses on the scalar path.
    const int wave_u = __builtin_amdgcn_readfirstlane((int)(threadIdx.x >> 6));
    const int r      = wave_u & 1;        // row slot within block (0..1)
    const int chalf  = wave_u >> 1;       // 0 / 1: which 32-channel half
    const int bh     = blockIdx.x * 2 + r;        // 0..223
    const int b      = bh / Hn;
    const int h      = bh - b * Hn;
    const int og     = blockIdx.y * OG;   // block-uniform o base

    const int wc     = lane;              // pixel column; lanes >=56 inactive
    const bool act   = wc < Wn;
    const int c1     = min(wc, Wn - 1);   // clamped own-tap address

    int acc[OG];
    #pragma unroll
    for (int i = 0; i < OG; ++i) acc[i] = 0;

    int nvalid = 0;
    const float* xb = x + b * (Cn * Hn * Wn) + chalf * (CH * Hn * Wn);

    for (int kh = 0; kh < 3; ++kh) {
        const int row = h + kh - 1;
        if (row < 0 || row >= Hn) continue;   // fully-pad row: sign(0)=0, skip
        ++nvalid;
        const float* xr = xb + row * Wn;
        #pragma unroll 8
        for (int c = 0; c < CH; ++c) {
            const float v  = xr[c * (Hn * Wn) + c1];  // one load per channel
            const float x1 = act ? v : 0.0f;          // zero lanes >=56
            const float x0 = dpp_shift(x1, 1);        // x[wc-1]; lane0 -> +0 pad
            const float x2 = dpp_shift(x1, 0);        // x[wc+1]; lane55 -> +0 pad
            #pragma unroll
            for (int oo = 0; oo < OG; ++oo) {
                // W[o,kw,kh,c] = wt[o*576 + kw*192 + kh*64 + c]; fully uniform
                // address -> s_load clusters on the scalar path.
                const float* wp = wt + (og + oo) * (3 * 3 * Cn) + kh * Cn
                                + chalf * CH + c;
                const float p0 = x0 * wp[0 * 3 * Cn];   // contract(off):
                const float p1 = x1 * wp[1 * 3 * Cn];   //   plain v_mul_f32,
                const float p2 = x2 * wp[2 * 3 * Cn];   //   no v_fmac fusion
                const float s  = (p0 + p1) + p2;        // same order as reference
                acc[oo] += (int)(__float_as_uint(s) >> 31);  // count negatives
            }
        }
    }

    // Combine the two c-halves' negative-counts (integer -> exact).
    if (chalf == 1) {
        #pragma unroll
        for (int oo = 0; oo < OG; ++oo) lds[r][oo][lane] = acc[oo];
    }
    __syncthreads();
    if (chalf == 0 && act) {
        float* ob = out + ((b * On + og) * Hn + h) * Wn + wc;
        const float base = (float)(nvalid * Cn);
        #pragma unroll
        for (int oo = 0; oo < OG; ++oo) {
            const int total = acc[oo] + lds[r][oo][lane];
            ob[oo * Hn * Wn] = base - 2.0f * (float)total;  // N - 2*negcount
        }
    }
}

extern "C" void kernel_launch(void* const* d_in, const int* in_sizes, int n_in,
                              void* d_out, int out_size, void* d_ws, size_t ws_size,
                              hipStream_t stream) {
    const float* x  = (const float*)d_in[0];
    const float* wt = (const float*)d_in[1];
    float* o        = (float*)d_out;
    dim3 grid(112, 16);   // 112 row-pair blocks x 16 o-groups of 4
    maj3_kernel<<<grid, dim3(256), 0, stream>>>(x, wt, o);
}

// Round 8
// 37.945 us; speedup vs baseline: 1.1779x; 1.0190x over previous
//
#include <hip/hip_runtime.h>

// Maj3: out[b,o,h,w] = sum_{kh,c} sign( sum_{kw} x[b,c,h+kh-1,w+kw-1] * W[o,kw,kh,c] )
// x: (4,64,56,56) f32; W: (64,3,3,64) f32; out: (4,64,56,56) f32.
// Bit-exactness vs numpy required (integer output, threshold 1.36): no FMA
// contraction (contract(off) pragma — verified holding, absmax stable 1.0),
// same per-channel mul/add order, sign(0)=0 only from fully-pad rows (skipped).
//
// R8: amortize per-channel tap prep (1 VMEM + cndmask + 2 DPP) over more
// output channels: OG 4->8, CH 32->16. Per-wave x loads halve (48), sign ops
// per prep double, wave count/balance unchanged (grid 224x8 = 7 blocks/CU,
// 28 waves/CU). Block = 4 waves = 4 c-quarters of one row; negcounts combined
// via 3-slab LDS (integer-exact). Tap neighbors via DPP wave shifts (R7).

#define Cn 64
#define Hn 56
#define Wn 56
#define On 64
#define OG 8    // output channels per block (uniform -> scalar weight loads)
#define CH 16   // channels per wave (c-quarter)

#define DPP_WAVE_SHL1 0x130
#define DPP_WAVE_SHR1 0x138

// Whole-wave shift by one lane; out-of-range source lanes read 0 (exact pad).
__device__ __forceinline__ float dpp_shift(float s, const int ctrl_is_shr) {
    const int si = __builtin_bit_cast(int, s);
    const int r  = ctrl_is_shr
        ? __builtin_amdgcn_update_dpp(0, si, DPP_WAVE_SHR1, 0xf, 0xf, true)
        : __builtin_amdgcn_update_dpp(0, si, DPP_WAVE_SHL1, 0xf, 0xf, true);
    return __builtin_bit_cast(float, r);
}

__global__ __launch_bounds__(256, 7)
void maj3_kernel(const float* __restrict__ x,
                 const float* __restrict__ wt,
                 float* __restrict__ out)
{
#pragma clang fp contract(off)
    __shared__ int lds[3][OG][64];   // slabs for c-quarters 1..3

    const int lane   = threadIdx.x & 63;
    // Wave-uniform; readfirstlane keeps rows/weight addresses on the scalar path.
    const int cq     = __builtin_amdgcn_readfirstlane((int)(threadIdx.x >> 6)); // 0..3
    const int bh     = blockIdx.x;        // 0..223: one (b,h) row per block
    const int b      = bh / Hn;
    const int h      = bh - b * Hn;
    const int og     = blockIdx.y * OG;   // block-uniform o base

    const int wc     = lane;              // pixel column; lanes >=56 inactive
    const bool act   = wc < Wn;
    const int c1     = min(wc, Wn - 1);   // clamped own-tap address

    int acc[OG];
    #pragma unroll
    for (int i = 0; i < OG; ++i) acc[i] = 0;

    int nvalid = 0;
    const float* xb = x + b * (Cn * Hn * Wn) + cq * (CH * Hn * Wn);

    for (int kh = 0; kh < 3; ++kh) {
        const int row = h + kh - 1;
        if (row < 0 || row >= Hn) continue;   // fully-pad row: sign(0)=0, skip
        ++nvalid;
        const float* xr = xb + row * Wn;
        #pragma unroll 4
        for (int c = 0; c < CH; ++c) {
            const float v  = xr[c * (Hn * Wn) + c1];  // one load per channel
            const float x1 = act ? v : 0.0f;          // zero lanes >=56
            const float x0 = dpp_shift(x1, 1);        // x[wc-1]; lane0 -> +0 pad
            const float x2 = dpp_shift(x1, 0);        // x[wc+1]; lane55 -> +0 pad
            #pragma unroll
            for (int oo = 0; oo < OG; ++oo) {
                // W[o,kw,kh,c] = wt[o*576 + kw*192 + kh*64 + c]; fully uniform
                // address -> s_load clusters on the scalar path.
                const float* wp = wt + (og + oo) * (3 * 3 * Cn) + kh * Cn
                                + cq * CH + c;
                const float p0 = x0 * wp[0 * 3 * Cn];   // contract(off):
                const float p1 = x1 * wp[1 * 3 * Cn];   //   plain v_mul_f32,
                const float p2 = x2 * wp[2 * 3 * Cn];   //   no v_fmac fusion
                const float s  = (p0 + p1) + p2;        // same order as reference
                acc[oo] += (int)(__float_as_uint(s) >> 31);  // count negatives
            }
        }
    }

    // Combine the four c-quarters' negative-counts (integer -> exact).
    if (cq != 0) {
        #pragma unroll
        for (int oo = 0; oo < OG; ++oo) lds[cq - 1][oo][lane] = acc[oo];
    }
    __syncthreads();
    if (cq == 0 && act) {
        float* ob = out + ((b * On + og) * Hn + h) * Wn + wc;
        const float base = (float)(nvalid * Cn);
        #pragma unroll
        for (int oo = 0; oo < OG; ++oo) {
            const int total = acc[oo] + lds[0][oo][lane]
                            + lds[1][oo][lane] + lds[2][oo][lane];
            ob[oo * Hn * Wn] = base - 2.0f * (float)total;  // N - 2*negcount
        }
    }
}

extern "C" void kernel_launch(void* const* d_in, const int* in_sizes, int n_in,
                              void* d_out, int out_size, void* d_ws, size_t ws_size,
                              hipStream_t stream) {
    const float* x  = (const float*)d_in[0];
    const float* wt = (const float*)d_in[1];
    float* o        = (float*)d_out;
    dim3 grid(224, 8);   // 224 (b,h) rows x 8 o-groups of 8
    maj3_kernel<<<grid, dim3(256), 0, stream>>>(x, wt, o);
}